// Round 10
// baseline (451.870 us; speedup 1.0000x reference)
//
#include <hip/hip_runtime.h>

// Problem constants
#define B_TOK 32768
#define D_IN  256
#define H1D   512
#define H2D   256
#define NE    16
#define NO    64

typedef _Float16 half8 __attribute__((ext_vector_type(8)));
typedef _Float16 half4 __attribute__((ext_vector_type(4)));
typedef float   float4_t  __attribute__((ext_vector_type(4)));
typedef float   float16_t __attribute__((ext_vector_type(16)));

// ---------------------------------------------------------------------------
// 32x32x16 f16 MFMA operand layouts (derived from verified 16x16x32 pattern):
//  A[m][k]: m = lane&31, k = (lane>>5)*8 + j   (8 halves, j in [0,8))
//  B[k][n]: n = lane&31, k = (lane>>5)*8 + j
//  C/D    : col = lane&31, row = (r&3) + 8*(r>>2) + 4*(lane>>5)  [measured m74/m101]
// All packed buffers are fragment-linear: one 512-half frag per (tile,ktile),
// lane*8 within -> every load/store is a contiguous b128/b64 per lane.
// ---------------------------------------------------------------------------

// Fused prep kernel (grid 2066 x 256):
//  blocks 0..1023    : pack W1 [E][D][H1] -> A-frags of W1^T (m=h1col,k=d)
//  blocks 1024..2047 : pack W2 [E][H1][H2] -> B-frags (k=h1col,n=h2col)
//  blocks 2048..2064 : w3h[e][h2] = W3[e][h2][:].head_w ; c3[e] = b3[e].head_w
//  block  2065       : pack gate_w [D][E] -> A-frags (m=e zero-padded to 32,k=d)
__global__ void prep_kernel(const float* __restrict__ W1, const float* __restrict__ W2,
                            const float* __restrict__ W3, const float* __restrict__ b3,
                            const float* __restrict__ hw, const float* __restrict__ gw,
                            _Float16* __restrict__ w1p, _Float16* __restrict__ w2p,
                            float* __restrict__ w3h, float* __restrict__ c3,
                            _Float16* __restrict__ gwp) {
  int blk = blockIdx.x;
  int tid = threadIdx.x;
  if (blk < 1024) {
    // w1p frag (e, ct[0,16), kd[0,16)) at ((e*16+ct)*16+kd)*512 + lane*8
    int t = blk * 256 + tid;                     // 262144 threads
    int lane = t & 63;
    int kd   = (t >> 6) & 15;
    int ct   = (t >> 10) & 15;
    int e    = t >> 14;
    int m  = ct * 32 + (lane & 31);              // h1 col
    int d0 = kd * 16 + (lane >> 5) * 8;
    half8 v;
    #pragma unroll
    for (int j = 0; j < 8; ++j)
      v[j] = (_Float16)W1[((size_t)(e * D_IN + d0 + j)) * H1D + m];
    *(half8*)(w1p + (size_t)t * 8) = v;
  } else if (blk < 2048) {
    // w2p frag (e, nc[0,8), kcg[0,32)) at ((e*8+nc)*32+kcg)*512 + lane*8
    int t = (blk - 1024) * 256 + tid;            // 262144 threads
    int lane = t & 63;
    int kcg  = (t >> 6) & 31;
    int nc   = (t >> 11) & 7;
    int e    = t >> 14;
    int n  = nc * 32 + (lane & 31);              // h2 col
    int k0 = kcg * 16 + (lane >> 5) * 8;         // h1 col
    half8 v;
    #pragma unroll
    for (int j = 0; j < 8; ++j)
      v[j] = (_Float16)W2[((size_t)(e * H1D + k0 + j)) * H2D + n];
    *(half8*)(w2p + (size_t)t * 8) = v;
  } else if (blk < 2065) {
    int t = (blk - 2048) * 256 + tid;
    if (t < NE * H2D) {
      int e = t >> 8, h = t & 255;
      float s = 0.f;
      #pragma unroll
      for (int o = 0; o < NO; ++o) s = fmaf(W3[((size_t)(e * H2D + h)) * NO + o], hw[o], s);
      w3h[t] = s;
    } else if (t < NE * H2D + NE) {
      int e = t - NE * H2D;
      float s = 0.f;
      #pragma unroll
      for (int o = 0; o < NO; ++o) s = fmaf(b3[e * NO + o], hw[o], s);
      c3[e] = s;
    }
  } else {
    // gwp frag (kd[0,16)) at kd*512 + lane*8 ; A[m=e(pad32)][k=d]
    for (int t = tid; t < 1024; t += 256) {
      int lane = t & 63;
      int kd   = t >> 6;
      int er = lane & 31;
      int d0 = kd * 16 + (lane >> 5) * 8;
      half8 v;
      #pragma unroll
      for (int j = 0; j < 8; ++j)
        v[j] = (er < NE) ? (_Float16)gw[(d0 + j) * NE + er] : (_Float16)0.f;
      *(half8*)(gwp + (size_t)t * 8) = v;
    }
  }
}

// ---------------------------------------------------------------------------
// Fused main kernel. 512 blocks x 256 threads (4 waves), 64 tokens/block,
// 2 blocks/CU. All MFMAs are 32x32x16 f16 (2x data reuse vs 16x16x32:
// halves LDS fragment traffic and weight bytes per FLOP; faster pipe).
// x staged once into LDS as B-frags (frag (tt,kd) = (tt*16+kd)*512).
// h1 chunk buffer (256 cols) in A-frag layout (frag (tt,kcl)).
// Per expert, per chunk: L1 (A=W1^T global frags, B=x LDS) -> h1c -> B1 ->
// L2 partial (A=h1c LDS, B=W2 global frags) -> B2 (WAR).
// Deferred-gate register epilogue; single shuffle-reduce at the end.
// ---------------------------------------------------------------------------
__global__ __launch_bounds__(256, 2) void moe_main(
    const float* __restrict__ x,
    const float* __restrict__ b1,
    const float* __restrict__ b2,
    const _Float16* __restrict__ w1p,
    const _Float16* __restrict__ w2p,
    const _Float16* __restrict__ gwp,
    const float* __restrict__ gb,
    const float* __restrict__ w3h,
    const float* __restrict__ c3,
    const float* __restrict__ head_b,
    float* __restrict__ out) {
  __shared__ _Float16 x_lds[32 * 512];             // 32 KB, B-frag linear
  __shared__ _Float16 h1c[32 * 512];               // 32 KB, A-frag linear chunk
  __shared__ float g_lds[64 * 17];                 // 4,352 B [token][e]
  __shared__ float fin[4 * 64];                    // 1,024 B

  const int tid  = threadIdx.x;
  const int w    = tid >> 6;                       // 0..3
  const int lane = tid & 63;
  const int l31  = lane & 31;
  const int hl   = lane >> 5;
  const int m0   = blockIdx.x * 64;

  // ---- stage x into B-frags: frag (tt,kd): lane holds
  //      x[tt*32 + (lane&31)][kd*16 + hl*8 .. +8]. Wave w stages frags w*8..+8.
  #pragma unroll
  for (int i = 0; i < 8; ++i) {
    int f  = w * 8 + i;                            // frag index [0,32)
    int tt = f >> 4, kd = f & 15;
    const float* xr = x + (size_t)(m0 + tt * 32 + l31) * D_IN + kd * 16 + hl * 8;
    float4_t v0 = *(const float4_t*)(xr);
    float4_t v1 = *(const float4_t*)(xr + 4);
    half8 h;
    h[0] = (_Float16)v0[0]; h[1] = (_Float16)v0[1];
    h[2] = (_Float16)v0[2]; h[3] = (_Float16)v0[3];
    h[4] = (_Float16)v1[0]; h[5] = (_Float16)v1[1];
    h[6] = (_Float16)v1[2]; h[7] = (_Float16)v1[3];
    *(half8*)(x_lds + (size_t)f * 512 + lane * 8) = h;
  }
  __syncthreads();   // x_lds ready

  // ---- gates: D[e][tok] = gate_w^T x^T via 32x32x16; waves 0,1 (tt = w) ----
  if (w < 2) {
    const int tt = w;
    float16_t lg;
    #pragma unroll
    for (int i = 0; i < 16; ++i) lg[i] = 0.f;
    #pragma unroll
    for (int kd = 0; kd < 16; ++kd) {
      half8 av = *(const half8*)(gwp + (size_t)kd * 512 + lane * 8);
      half8 xv = *(const half8*)(x_lds + (size_t)(tt * 16 + kd) * 512 + lane * 8);
      lg = __builtin_amdgcn_mfma_f32_32x32x16_f16(av, xv, lg, 0, 0, 0);
    }
    int tok = tt * 32 + l31;
    #pragma unroll
    for (int r = 0; r < 8; ++r) {                  // rows with e < 16
      int ee = 4 * hl + (r & 3) + 8 * (r >> 2);
      g_lds[tok * 17 + ee] = lg[r] + gb[ee];
    }
  }
  __syncthreads();   // logits visible
  if (tid < 64) {    // per-token softmax over 16 experts
    float mx = g_lds[tid * 17];
    #pragma unroll
    for (int e = 1; e < NE; ++e) mx = fmaxf(mx, g_lds[tid * 17 + e]);
    float sm = 0.f;
    #pragma unroll
    for (int e = 0; e < NE; ++e) {
      float p = __expf(g_lds[tid * 17 + e] - mx);
      g_lds[tid * 17 + e] = p;
      sm += p;
    }
    float inv = 1.f / sm;
    #pragma unroll
    for (int e = 0; e < NE; ++e) g_lds[tid * 17 + e] *= inv;
  }
  // softmax writes are published by the first in-loop barrier before any read.

  float yacc[2][16];   // [tt][r] gated accumulator (token = tt*32 + row(r,hl))
  #pragma unroll
  for (int tt = 0; tt < 2; ++tt)
    #pragma unroll
    for (int r = 0; r < 16; ++r) yacc[tt][r] = 0.f;

  for (int e = 0; e < NE; ++e) {
    float16_t h2[2][2];   // [tt][ncl], accumulates across both chunks
    #pragma unroll
    for (int tt = 0; tt < 2; ++tt)
      #pragma unroll
      for (int ncl = 0; ncl < 2; ++ncl)
        #pragma unroll
        for (int i = 0; i < 16; ++i) h2[tt][ncl][i] = 0.f;

    #pragma unroll
    for (int ch = 0; ch < 2; ++ch) {
      // ===== L1 chunk: D[h1col][token]; wave w -> chunk col-tiles {2w,2w+1} ==
      float16_t a1[2][2];   // [ctl][tt]
      #pragma unroll
      for (int ctl = 0; ctl < 2; ++ctl)
        #pragma unroll
        for (int tt = 0; tt < 2; ++tt)
          #pragma unroll
          for (int i = 0; i < 16; ++i) a1[ctl][tt][i] = 0.f;

      const _Float16* w1e =
          w1p + ((size_t)((e * 16 + ch * 8 + w * 2) * 16)) * 512 + lane * 8;
      #pragma unroll
      for (int kd = 0; kd < 16; ++kd) {
        half8 wA[2];
        wA[0] = *(const half8*)(w1e + (size_t)kd * 512);
        wA[1] = *(const half8*)(w1e + (size_t)(16 + kd) * 512);
        half8 xB[2];
        xB[0] = *(const half8*)(x_lds + (size_t)kd * 512 + lane * 8);
        xB[1] = *(const half8*)(x_lds + (size_t)(16 + kd) * 512 + lane * 8);
        #pragma unroll
        for (int ctl = 0; ctl < 2; ++ctl)
          #pragma unroll
          for (int tt = 0; tt < 2; ++tt)
            a1[ctl][tt] = __builtin_amdgcn_mfma_f32_32x32x16_f16(
                wA[ctl], xB[tt], a1[ctl][tt], 0, 0, 0);
      }

      // bias + relu + half4 stores into A-frag-linear h1c.
      // a1[ctl][tt][r]: token = tt*32 + (lane&31); h1 chunk col
      // c = (w*2+ctl)*32 + 8*g + 4*hl + (r&3), g = r>>2 (runs of 4).
      // Dest: frag (tt, ct_local*2 + (g>>1)), lane' = (l&31)+32*(g&1),
      // half-offset 4*hl. (verified vs A-operand reader mapping)
      #pragma unroll
      for (int ctl = 0; ctl < 2; ++ctl) {
        int ct_local = w * 2 + ctl;                // [0,8)
        #pragma unroll
        for (int g = 0; g < 4; ++g) {
          int colbase = (ch * 8 + ct_local) * 32 + 8 * g + 4 * hl;  // global col
          float4_t bb = *(const float4_t*)(b1 + e * H1D + colbase);
          _Float16* dst = h1c + (size_t)(ct_local * 2 + (g >> 1)) * 512 +
                          (size_t)(l31 + 32 * (g & 1)) * 8 + 4 * hl;
          #pragma unroll
          for (int tt = 0; tt < 2; ++tt) {
            half4 hv;
            #pragma unroll
            for (int r4 = 0; r4 < 4; ++r4)
              hv[r4] = (_Float16)fmaxf(a1[ctl][tt][g * 4 + r4] + bb[r4], 0.f);
            *(half4*)(dst + (size_t)tt * (16 * 512)) = hv;
          }
        }
      }

      __syncthreads();   // B1: h1 chunk ready

      // ===== L2 partial: D[token][h2col]; wave w -> h2col-tiles {2w,2w+1} ===
      const _Float16* w2e =
          w2p + ((size_t)((e * 8 + w * 2) * 32 + ch * 16)) * 512 + lane * 8;
      #pragma unroll
      for (int kcl = 0; kcl < 16; ++kcl) {
        half8 wB[2];
        wB[0] = *(const half8*)(w2e + (size_t)kcl * 512);
        wB[1] = *(const half8*)(w2e + (size_t)(32 + kcl) * 512);
        half8 hA[2];
        hA[0] = *(const half8*)(h1c + (size_t)kcl * 512 + lane * 8);
        hA[1] = *(const half8*)(h1c + (size_t)(16 + kcl) * 512 + lane * 8);
        #pragma unroll
        for (int tt = 0; tt < 2; ++tt)
          #pragma unroll
          for (int ncl = 0; ncl < 2; ++ncl)
            h2[tt][ncl] = __builtin_amdgcn_mfma_f32_32x32x16_f16(
                hA[tt], wB[ncl], h2[tt][ncl], 0, 0, 0);
      }

      __syncthreads();   // B2 (WAR): h1c reads done before next chunk/expert
    }

    // ---- register epilogue: relu(h2+b2).w3h, gate folded, accumulate ------
    float b2v[2], w3v[2];
    #pragma unroll
    for (int ncl = 0; ncl < 2; ++ncl) {
      int col = (w * 2 + ncl) * 32 + l31;
      b2v[ncl] = b2[e * H2D + col];
      w3v[ncl] = w3h[e * H2D + col];
    }
    #pragma unroll
    for (int tt = 0; tt < 2; ++tt) {
      #pragma unroll
      for (int r = 0; r < 16; ++r) {
        float s = fmaxf(h2[tt][0][r] + b2v[0], 0.f) * w3v[0] +
                  fmaxf(h2[tt][1][r] + b2v[1], 0.f) * w3v[1];
        int tok = tt * 32 + 4 * hl + (r & 3) + 8 * (r >> 2);
        yacc[tt][r] += g_lds[tok * 17 + e] * s;
      }
    }
  }

  // ---- final: reduce yacc over the 32 col-lanes (h2cols), then cross-wave --
  #pragma unroll
  for (int tt = 0; tt < 2; ++tt) {
    #pragma unroll
    for (int r = 0; r < 16; ++r) {
      float v = yacc[tt][r];
      v += __shfl_xor(v, 1);
      v += __shfl_xor(v, 2);
      v += __shfl_xor(v, 4);
      v += __shfl_xor(v, 8);
      v += __shfl_xor(v, 16);
      if (l31 == 0) {
        int tok = tt * 32 + 4 * hl + (r & 3) + 8 * (r >> 2);
        fin[w * 64 + tok] = v;
      }
    }
  }
  __syncthreads();
  if (tid < 64) {
    float sum = fin[tid] + fin[64 + tid] + fin[128 + tid] + fin[192 + tid];
    float gc = 0.f;
    #pragma unroll
    for (int e = 0; e < NE; ++e) gc += g_lds[tid * 17 + e] * c3[e];
    out[m0 + tid] = sum + gc + head_b[0];
  }
}

// ---------------------------------------------------------------------------
extern "C" void kernel_launch(void* const* d_in, const int* in_sizes, int n_in,
                              void* d_out, int out_size, void* d_ws, size_t ws_size,
                              hipStream_t stream) {
  const float* x      = (const float*)d_in[0];
  const float* gate_w = (const float*)d_in[1];
  const float* gate_b = (const float*)d_in[2];
  const float* W1     = (const float*)d_in[3];
  const float* b1     = (const float*)d_in[4];
  const float* W2     = (const float*)d_in[5];
  const float* b2     = (const float*)d_in[6];
  const float* W3     = (const float*)d_in[7];
  const float* b3     = (const float*)d_in[8];
  const float* head_w = (const float*)d_in[9];
  const float* head_b = (const float*)d_in[10];
  float* out = (float*)d_out;

  // workspace layout (16B-aligned)
  char* ws = (char*)d_ws;
  _Float16* w1p = (_Float16*)(ws);                 // 4,194,304 B
  _Float16* w2p = (_Float16*)(ws + 4194304);       // 4,194,304 B
  _Float16* gwp = (_Float16*)(ws + 8388608);       // 16,384 B
  float*    w3h = (float*)(ws + 8404992);          // 16,384 B
  float*    c3  = (float*)(ws + 8421376);          // 64 B

  hipLaunchKernelGGL(prep_kernel, dim3(2066), dim3(256), 0, stream,
                     W1, W2, W3, b3, head_w, gate_w, w1p, w2p, w3h, c3, gwp);
  hipLaunchKernelGGL(moe_main, dim3(B_TOK / 64), dim3(256), 0, stream,
                     x, b1, b2, w1p, w2p, gwp, gate_b, w3h, c3, head_b, out);
}

// Round 11
// 431.343 us; speedup vs baseline: 1.0476x; 1.0476x over previous
//
#include <hip/hip_runtime.h>

// Problem constants
#define B_TOK 32768
#define D_IN  256
#define H1D   512
#define H2D   256
#define NE    16
#define NO    64

typedef _Float16 half8 __attribute__((ext_vector_type(8)));
typedef _Float16 half4 __attribute__((ext_vector_type(4)));
typedef float   float4_t __attribute__((ext_vector_type(4)));

// ---------------------------------------------------------------------------
// Fused prep kernel (grid 2066 x 256)  [R8-proven 16x16x32 layouts]:
//  blocks 0..1023    : pack W1 [E][D][H1] fp32 -> fragment-linear fp16
//  blocks 1024..2047 : pack W2 [E][H1][H2] fp32 -> fragment-linear fp16
//  blocks 2048..2064 : w3h[e][h2] = W3[e][h2][:].head_w ; c3[e] = b3[e].head_w
//  block  2065       : pack gate_w [D][E] -> 8 B-fragments
// ---------------------------------------------------------------------------
__global__ void prep_kernel(const float* __restrict__ W1, const float* __restrict__ W2,
                            const float* __restrict__ W3, const float* __restrict__ b3,
                            const float* __restrict__ hw, const float* __restrict__ gw,
                            _Float16* __restrict__ w1p, _Float16* __restrict__ w2p,
                            float* __restrict__ w3h, float* __restrict__ c3,
                            _Float16* __restrict__ gwp) {
  int blk = blockIdx.x;
  int tid = threadIdx.x;
  if (blk < 1024) {
    int t = blk * 256 + tid;                     // 262144 threads
    int lane = t & 63;
    int kt   = (t >> 6) & 7;
    int ntg  = (t >> 9) & 31;
    int e    = t >> 14;
    int n  = ntg * 16 + (lane & 15);
    int kb = kt * 32 + (lane >> 4) * 8;
    half8 v;
    #pragma unroll
    for (int j = 0; j < 8; ++j)
      v[j] = (_Float16)W1[((size_t)(e * D_IN + kb + j)) * H1D + n];
    *(half8*)(w1p + (size_t)t * 8) = v;
  } else if (blk < 2048) {
    int t = (blk - 1024) * 256 + tid;            // 262144 threads
    int lane = t & 63;
    int ktg  = (t >> 6) & 15;
    int ntg  = (t >> 10) & 15;
    int e    = t >> 14;
    int n  = ntg * 16 + (lane & 15);
    int kb = ktg * 32 + (lane >> 4) * 8;
    half8 v;
    #pragma unroll
    for (int j = 0; j < 8; ++j)
      v[j] = (_Float16)W2[((size_t)(e * H1D + kb + j)) * H2D + n];
    *(half8*)(w2p + (size_t)t * 8) = v;
  } else if (blk < 2065) {
    int t = (blk - 2048) * 256 + tid;
    if (t < NE * H2D) {
      int e = t >> 8, h = t & 255;
      float s = 0.f;
      #pragma unroll
      for (int o = 0; o < NO; ++o) s = fmaf(W3[((size_t)(e * H2D + h)) * NO + o], hw[o], s);
      w3h[t] = s;
    } else if (t < NE * H2D + NE) {
      int e = t - NE * H2D;
      float s = 0.f;
      #pragma unroll
      for (int o = 0; o < NO; ++o) s = fmaf(b3[e * NO + o], hw[o], s);
      c3[e] = s;
    }
  } else {
    for (int t = tid; t < 512; t += 256) {
      int lane = t & 63;
      int kt   = t >> 6;
      int e  = lane & 15;
      int kb = kt * 32 + (lane >> 4) * 8;
      half8 v;
      #pragma unroll
      for (int j = 0; j < 8; ++j)
        v[j] = (_Float16)gw[(kb + j) * NE + e];
      *(half8*)(gwp + (size_t)t * 8) = v;
    }
  }
}

// ---------------------------------------------------------------------------
// Fused main kernel. 512 blocks x 256 threads (4 waves), 64 tokens/block,
// TARGET 3 blocks/CU (12 waves, 3/SIMD) for latency hiding.
// LDS trimmed to 53.25 KB: x frags 32 KB + 128-col h1 chunk 16 KB +
// gates 4 KB; final-reduction buffer aliased onto h1c.
// All MFMAs 16x16x32 f16 (R8-proven). Per expert, 4 chunks of 128 h1-cols:
//   L1c (A=W1^T global frags, B=x LDS frags) -> frag-linear h1c -> B1 ->
//   L2c partial (A=h1c frags, B=W2 global frags) -> B2 (WAR)
// Deferred-gate register epilogue; single shuffle-reduce at the end.
// ---------------------------------------------------------------------------
__global__ __launch_bounds__(256, 3) void moe_main(
    const float* __restrict__ x,
    const float* __restrict__ b1,
    const float* __restrict__ b2,
    const _Float16* __restrict__ w1p,
    const _Float16* __restrict__ w2p,
    const _Float16* __restrict__ gwp,
    const float* __restrict__ gb,
    const float* __restrict__ w3h,
    const float* __restrict__ c3,
    const float* __restrict__ head_b,
    float* __restrict__ out) {
  __shared__ _Float16 x_lds[32 * 512];             // 32 KB, B/A-frag linear
  __shared__ _Float16 h1c[16 * 512];               // 16 KB, A-frag linear chunk
  __shared__ float g_lds[64 * 16];                 // 4 KB [token][e]

  float* fin = (float*)h1c;                        // aliased: used only at end

  const int tid  = threadIdx.x;
  const int w    = tid >> 6;
  const int lane = tid & 63;
  const int q    = lane >> 4;
  const int l16  = lane & 15;
  const int m0   = blockIdx.x * 64;

  // ---- stage x into frag-linear LDS: frag (nt,kt) at (nt*8+kt)*512 + lane*8
  #pragma unroll
  for (int f = 0; f < 8; ++f) {
    const float* xr = x + (size_t)(m0 + w * 16 + l16) * D_IN + f * 32 + q * 8;
    float4_t v0 = *(const float4_t*)(xr);
    float4_t v1 = *(const float4_t*)(xr + 4);
    half8 h;
    h[0] = (_Float16)v0[0]; h[1] = (_Float16)v0[1];
    h[2] = (_Float16)v0[2]; h[3] = (_Float16)v0[3];
    h[4] = (_Float16)v1[0]; h[5] = (_Float16)v1[1];
    h[6] = (_Float16)v1[2]; h[7] = (_Float16)v1[3];
    *(half8*)(x_lds + (size_t)(w * 8 + f) * 512 + lane * 8) = h;
  }
  __syncthreads();   // x_lds ready

  // ---- gates via MFMA + shuffle softmax; wave w handles token tile w ------
  {
    float gbv = gb[l16];
    float4_t lg = (float4_t){0.f, 0.f, 0.f, 0.f};
    #pragma unroll
    for (int kt = 0; kt < 8; ++kt) {
      half8 xa = *(const half8*)(x_lds + (size_t)(w * 8 + kt) * 512 + lane * 8);
      half8 bfr = *(const half8*)(gwp + (size_t)kt * 512 + lane * 8);
      lg = __builtin_amdgcn_mfma_f32_16x16x32_f16(xa, bfr, lg, 0, 0, 0);
    }
    #pragma unroll
    for (int r = 0; r < 4; ++r) {
      float v = lg[r] + gbv;                       // logit[token][e=l16]
      float m = v;
      m = fmaxf(m, __shfl_xor(m, 1));
      m = fmaxf(m, __shfl_xor(m, 2));
      m = fmaxf(m, __shfl_xor(m, 4));
      m = fmaxf(m, __shfl_xor(m, 8));
      float p = __expf(v - m);
      float s = p;
      s += __shfl_xor(s, 1);
      s += __shfl_xor(s, 2);
      s += __shfl_xor(s, 4);
      s += __shfl_xor(s, 8);
      g_lds[(w * 16 + q * 4 + r) * 16 + l16] = p / s;
    }
  }
  // g_lds published by the first in-loop barrier before any epilogue read.

  float yacc[4][4];    // gated accumulator: [mt][r] for token mt*16+q*4+r
  #pragma unroll
  for (int mt = 0; mt < 4; ++mt)
    #pragma unroll
    for (int r = 0; r < 4; ++r) yacc[mt][r] = 0.f;

  for (int e = 0; e < NE; ++e) {
    float4_t h2[4][4];   // accumulates across the 4 chunks
    #pragma unroll
    for (int mt = 0; mt < 4; ++mt)
      #pragma unroll
      for (int nt = 0; nt < 4; ++nt)
        h2[mt][nt] = (float4_t){0.f, 0.f, 0.f, 0.f};

    #pragma unroll
    for (int c = 0; c < 4; ++c) {
      // ===== L1 chunk: h1 cols [c*128, +128); wave w -> col-tiles {2w,2w+1} =
      float4_t a1[2][4];   // [i = col tile][nt = token tile]
      #pragma unroll
      for (int i = 0; i < 2; ++i)
        #pragma unroll
        for (int nt = 0; nt < 4; ++nt)
          a1[i][nt] = (float4_t){0.f, 0.f, 0.f, 0.f};

      const _Float16* w1e =
          w1p + ((size_t)((e * 32 + c * 8 + w * 2) * 8)) * 512 + lane * 8;
      #pragma unroll
      for (int kt = 0; kt < 8; ++kt) {
        half8 wc[2];
        wc[0] = *(const half8*)(w1e + (size_t)kt * 512);
        wc[1] = *(const half8*)(w1e + (size_t)(8 + kt) * 512);
        half8 xb[4];
        #pragma unroll
        for (int nt = 0; nt < 4; ++nt)
          xb[nt] = *(const half8*)(x_lds + (size_t)(nt * 8 + kt) * 512 + lane * 8);
        #pragma unroll
        for (int i = 0; i < 2; ++i)
          #pragma unroll
          for (int nt = 0; nt < 4; ++nt)
            a1[i][nt] = __builtin_amdgcn_mfma_f32_16x16x32_f16(
                wc[i], xb[nt], a1[i][nt], 0, 0, 0);
      }

      // bias + relu + half4 stores into frag-linear h1c (R9-verified algebra):
      // a1[i][nt][r] = h1[tok=nt*16+l16][chunk col = (2w+i)*16 + q*4 + r]
      // dest frag (nt, kc=w), lane' q' = 2i + (q>>1), half-off (q&1)*4 + r.
      #pragma unroll
      for (int i = 0; i < 2; ++i) {
        int colbase = c * 128 + (w * 2 + i) * 16 + q * 4;    // global h1 col
        float4_t bb = *(const float4_t*)(b1 + e * H1D + colbase);
        int qp = (i << 1) + (q >> 1);
        int fo = (qp * 16 + l16) * 8 + ((q & 1) << 2);
        #pragma unroll
        for (int nt = 0; nt < 4; ++nt) {
          half4 hv;
          #pragma unroll
          for (int r = 0; r < 4; ++r)
            hv[r] = (_Float16)fmaxf(a1[i][nt][r] + bb[r], 0.f);
          *(half4*)(h1c + (size_t)(nt * 4 + w) * 512 + fo) = hv;
        }
      }

      __syncthreads();   // B1: h1 chunk ready

      // ===== L2 partial: wave w -> h2col-tiles {4w..4w+3}, 4 k-tiles ========
      const _Float16* w2e =
          w2p + ((size_t)((e * 16 + w * 4) * 16 + c * 4)) * 512 + lane * 8;
      #pragma unroll
      for (int kt = 0; kt < 4; ++kt) {
        half8 w2c[4];
        #pragma unroll
        for (int nt = 0; nt < 4; ++nt)
          w2c[nt] = *(const half8*)(w2e + (size_t)(nt * 16 + kt) * 512);
        half8 hac[4];
        #pragma unroll
        for (int mt = 0; mt < 4; ++mt)
          hac[mt] = *(const half8*)(h1c + (size_t)(mt * 4 + kt) * 512 + lane * 8);
        #pragma unroll
        for (int mt = 0; mt < 4; ++mt)
          #pragma unroll
          for (int nt = 0; nt < 4; ++nt)
            h2[mt][nt] = __builtin_amdgcn_mfma_f32_16x16x32_f16(
                hac[mt], w2c[nt], h2[mt][nt], 0, 0, 0);
      }

      __syncthreads();   // B2 (WAR): h1c reads done before next chunk/expert
    }

    // ---- register epilogue: relu(h2+b2).w3h, gate folded, accumulate ------
    float b2v[4], w3v[4];
    #pragma unroll
    for (int nt = 0; nt < 4; ++nt) {
      int n = w * 64 + nt * 16 + l16;
      b2v[nt] = b2[e * H2D + n];
      w3v[nt] = w3h[e * H2D + n];
    }
    #pragma unroll
    for (int mt = 0; mt < 4; ++mt) {
      #pragma unroll
      for (int r = 0; r < 4; ++r) {
        float s = 0.f;
        #pragma unroll
        for (int nt = 0; nt < 4; ++nt)
          s += fmaxf(h2[mt][nt][r] + b2v[nt], 0.f) * w3v[nt];
        yacc[mt][r] += g_lds[(mt * 16 + q * 4 + r) * 16 + e] * s;
      }
    }
  }

  // ---- single final reduction: sum yacc over the 16 l16-lanes (cols) ------
  // fin aliases h1c: every h1c read is sealed by the last B2 above, and all
  // fin writes occur after that barrier in program order on every wave.
  #pragma unroll
  for (int mt = 0; mt < 4; ++mt) {
    #pragma unroll
    for (int r = 0; r < 4; ++r) {
      float v = yacc[mt][r];
      v += __shfl_xor(v, 1);
      v += __shfl_xor(v, 2);
      v += __shfl_xor(v, 4);
      v += __shfl_xor(v, 8);
      yacc[mt][r] = v;
    }
  }
  if (l16 == 0) {
    #pragma unroll
    for (int mt = 0; mt < 4; ++mt)
      #pragma unroll
      for (int r = 0; r < 4; ++r)
        fin[w * 64 + mt * 16 + q * 4 + r] = yacc[mt][r];
  }
  __syncthreads();
  if (tid < 64) {
    float sum = fin[tid] + fin[64 + tid] + fin[128 + tid] + fin[192 + tid];
    float gc = 0.f;
    #pragma unroll
    for (int e = 0; e < NE; ++e) gc += g_lds[tid * 16 + e] * c3[e];
    out[m0 + tid] = sum + gc + head_b[0];
  }
}

// ---------------------------------------------------------------------------
extern "C" void kernel_launch(void* const* d_in, const int* in_sizes, int n_in,
                              void* d_out, int out_size, void* d_ws, size_t ws_size,
                              hipStream_t stream) {
  const float* x      = (const float*)d_in[0];
  const float* gate_w = (const float*)d_in[1];
  const float* gate_b = (const float*)d_in[2];
  const float* W1     = (const float*)d_in[3];
  const float* b1     = (const float*)d_in[4];
  const float* W2     = (const float*)d_in[5];
  const float* b2     = (const float*)d_in[6];
  const float* W3     = (const float*)d_in[7];
  const float* b3     = (const float*)d_in[8];
  const float* head_w = (const float*)d_in[9];
  const float* head_b = (const float*)d_in[10];
  float* out = (float*)d_out;

  // workspace layout (16B-aligned)
  char* ws = (char*)d_ws;
  _Float16* w1p = (_Float16*)(ws);                 // 4,194,304 B
  _Float16* w2p = (_Float16*)(ws + 4194304);       // 4,194,304 B
  _Float16* gwp = (_Float16*)(ws + 8388608);       // 8,192 B
  float*    w3h = (float*)(ws + 8396800);          // 16,384 B
  float*    c3  = (float*)(ws + 8413184);          // 64 B

  hipLaunchKernelGGL(prep_kernel, dim3(2066), dim3(256), 0, stream,
                     W1, W2, W3, b3, head_w, gate_w, w1p, w2p, w3h, c3, gwp);
  hipLaunchKernelGGL(moe_main, dim3(B_TOK / 64), dim3(256), 0, stream,
                     x, b1, b2, w1p, w2p, gwp, gate_b, w3h, c3, head_b, out);
}